// Round 1
// baseline (26607.214 us; speedup 1.0000x reference)
//
#include <hip/hip_runtime.h>
#include <math.h>

// Round 0: correctness-first fully-fused f32 implementation.
// One node per 256-thread block. All heavy matmuls are f32 VALU (floor ~5.3ms);
// Round 1+ will MFMA-ize phase C (Wk/Wv = 95% of FLOPs) once the accuracy
// margin is measured.

#define KNB 20
#define DN 128
#define DT 128
#define DE 128
#define DQ 256
#define DKV 384
#define HD 128

// mask dtype sniff: int32 0/1 values have all bytes at (i&3)!=0 equal to 0;
// 1-byte bools have random nonzero bytes there (P[all zero] = 2^-192).
__global__ void sniff_mask_kernel(const unsigned char* mb, int* flag) {
  if (blockIdx.x == 0 && threadIdx.x == 0) {
    int nz = 0;
    for (int i = 0; i < 256; ++i)
      if ((i & 3) != 0 && mb[i] != 0) nz = 1;
    *flag = nz ? 0 : 1;  // 1 => int32 mask, 0 => byte mask
  }
}

__global__ __launch_bounds__(256, 2)
void tgat_fused(const int* __restrict__ idx, const float* __restrict__ t,
                const int* __restrict__ neighbors, const float* __restrict__ e_t,
                const int* __restrict__ e_id, const void* __restrict__ mask_raw,
                const float* __restrict__ node_feat, const float* __restrict__ memv,
                const float* __restrict__ event_feat,
                const float* __restrict__ time_w, const float* __restrict__ time_b,
                const float* __restrict__ Wq, const float* __restrict__ bq,
                const float* __restrict__ Wk, const float* __restrict__ bk,
                const float* __restrict__ Wv, const float* __restrict__ bv,
                const float* __restrict__ Wo, const float* __restrict__ bo,
                const float* __restrict__ W1, const float* __restrict__ b1,
                const float* __restrict__ W2, const float* __restrict__ b2,
                float* __restrict__ out, const int* __restrict__ mask_flag)
{
  const int node = blockIdx.x;
  const int tid  = threadIdx.x;

  __shared__ __align__(16) float kvc[KNB][DKV];        // 30.7 KB
  __shared__ __align__(16) float qc_sh[DQ];
  __shared__ __align__(16) float q_sh[DN];
  __shared__ __align__(16) float qh_sh[DQ];
  __shared__ __align__(16) float kh_sh[KNB][DQ + 2];   // +2 pad: phase-D bank spread
  __shared__ __align__(16) float vh_sh[KNB][DQ + 2];
  __shared__ float scores_sh[2][KNB];
  __shared__ float attn_sh[2][KNB];
  __shared__ __align__(16) float out_sh[DQ];
  __shared__ __align__(16) float ao_sh[DQ];
  __shared__ __align__(16) float h1_sh[DN];
  __shared__ int msk_sh[KNB];

  // ---- mask load (dtype resolved by sniff flag in d_ws) ----
  if (tid < KNB) {
    int m;
    if (*mask_flag) m = ((const int*)mask_raw)[node * KNB + tid] != 0;
    else            m = ((const unsigned char*)mask_raw)[node * KNB + tid] != 0;
    msk_sh[tid] = m;
  }
  __syncthreads();

  int nb_any = 0;
  #pragma unroll
  for (int k = 0; k < KNB; ++k) nb_any |= msk_sh[k];

  const int   qi = idx[node];
  const float tq = t[node];

  // ---- phase A: build qc (q | cos(b)) and kvc (n_emb | kv_time | kv_event) ----
  if (tid < DN) {
    float qv = node_feat[(size_t)qi * DN + tid] + memv[(size_t)qi * DN + tid];
    q_sh[tid]  = qv;
    qc_sh[tid] = qv;
  } else {
    int d = tid - DN;
    // q_time = cos(0*w + b) = cos(b): constant across nodes
    qc_sh[DN + d] = cosf(time_b[d]);
  }
  {
    const int g = tid >> 7;        // 2 row-groups of 128 threads
    const int d = tid & 127;
    const float twd = time_w[d];
    const float tbd = time_b[d];
    for (int r = g; r < KNB; r += 2) {
      float ne = 0.f;
      if (msk_sh[r]) {             // masked rows contribute exact 0 (ref: *mask)
        int nb = neighbors[node * KNB + r];
        ne = node_feat[(size_t)nb * DN + d] + memv[(size_t)nb * DN + d];
      }
      kvc[r][d] = ne;
      float dt = tq - e_t[node * KNB + r];
      kvc[r][DN + d] = cosf(dt * twd + tbd);      // kv_time for ALL rows (ref)
      int ev = e_id[node * KNB + r];
      kvc[r][DN + DT + d] = event_feat[(size_t)ev * DE + d];  // ALL rows (ref)
    }
  }
  __syncthreads();

  // ---- phase B: qh = qc @ Wq.T + bq (thread o = output dim) ----
  {
    const float* wrow = Wq + tid * DQ;
    float acc = bq[tid];
    for (int i = 0; i < DQ; i += 4) {
      float4 w4 = *(const float4*)(wrow + i);
      float4 x4 = *(const float4*)(qc_sh + i);
      acc += x4.x * w4.x + x4.y * w4.y + x4.z * w4.z + x4.w * w4.w;
    }
    qh_sh[tid] = acc;
  }

  // ---- phase C: kh,vh = kvc @ {Wk,Wv}.T + b (20 rows per thread-column) ----
  {
    float acck[KNB], accv[KNB];
    const float bkv = bk[tid], bvv = bv[tid];
    #pragma unroll
    for (int r = 0; r < KNB; ++r) { acck[r] = bkv; accv[r] = bvv; }
    const float* wkrow = Wk + tid * DKV;
    const float* wvrow = Wv + tid * DKV;
    for (int i = 0; i < DKV; i += 4) {
      float4 wk4 = *(const float4*)(wkrow + i);
      float4 wv4 = *(const float4*)(wvrow + i);
      #pragma unroll
      for (int r = 0; r < KNB; ++r) {
        float4 c4 = *(const float4*)(&kvc[r][i]);   // uniform addr: LDS broadcast
        acck[r] += c4.x * wk4.x + c4.y * wk4.y + c4.z * wk4.z + c4.w * wk4.w;
        accv[r] += c4.x * wv4.x + c4.y * wv4.y + c4.z * wv4.z + c4.w * wv4.w;
      }
    }
    #pragma unroll
    for (int r = 0; r < KNB; ++r) { kh_sh[r][tid] = acck[r]; vh_sh[r][tid] = accv[r]; }
  }
  __syncthreads();

  // ---- phase D: scores + masking + softmax ----
  if (tid < 2 * KNB) {            // 40 threads, all in wave 0
    int h = tid / KNB;
    int k = tid - h * KNB;
    float s = 0.f;
    for (int d2 = 0; d2 < HD; ++d2)
      s += qh_sh[h * HD + d2] * kh_sh[k][h * HD + d2];
    s *= 0.088388347648318447f;   // 1/sqrt(128)
    int valid = msk_sh[k] | (nb_any ^ 1);   // rows w/o neighbors attend everywhere
    scores_sh[h][k] = valid ? s : -1e9f;
  }
  __syncthreads();
  if (tid < 2) {
    float mx = -3.4e38f;
    for (int k = 0; k < KNB; ++k) mx = fmaxf(mx, scores_sh[tid][k]);
    float ex[KNB]; float sum = 0.f;
    for (int k = 0; k < KNB; ++k) { ex[k] = expf(scores_sh[tid][k] - mx); sum += ex[k]; }
    float inv = 1.f / sum;
    for (int k = 0; k < KNB; ++k) attn_sh[tid][k] = ex[k] * inv;
  }
  __syncthreads();

  // ---- phase E: out = attn @ vh ; then @ Wo.T + bo ; zero no-neighbor rows ----
  {
    const int h = tid >> 7;
    float acc = 0.f;
    #pragma unroll
    for (int k = 0; k < KNB; ++k) acc += attn_sh[h][k] * vh_sh[k][tid];
    out_sh[tid] = acc;
  }
  __syncthreads();
  {
    const float* wrow = Wo + tid * DQ;
    float acc = bo[tid];
    for (int i = 0; i < DQ; i += 4) {
      float4 w4 = *(const float4*)(wrow + i);
      float4 x4 = *(const float4*)(out_sh + i);
      acc += x4.x * w4.x + x4.y * w4.y + x4.z * w4.z + x4.w * w4.w;
    }
    ao_sh[tid] = nb_any ? acc : 0.f;
  }
  __syncthreads();

  // ---- phase F: merger MLP ----
  if (tid < DN) {
    const float* wrow = W1 + tid * (DQ + DN);
    float acc = b1[tid];
    for (int i = 0; i < DQ; i += 4) {
      float4 w4 = *(const float4*)(wrow + i);
      float4 x4 = *(const float4*)(ao_sh + i);
      acc += x4.x * w4.x + x4.y * w4.y + x4.z * w4.z + x4.w * w4.w;
    }
    for (int i = 0; i < DN; i += 4) {
      float4 w4 = *(const float4*)(wrow + DQ + i);
      float4 x4 = *(const float4*)(q_sh + i);
      acc += x4.x * w4.x + x4.y * w4.y + x4.z * w4.z + x4.w * w4.w;
    }
    h1_sh[tid] = fmaxf(acc, 0.f);
  }
  __syncthreads();
  if (tid < DN) {
    const float* wrow = W2 + tid * DN;
    float acc = b2[tid];
    for (int i = 0; i < DN; i += 4) {
      float4 w4 = *(const float4*)(wrow + i);
      float4 x4 = *(const float4*)(h1_sh + i);
      acc += x4.x * w4.x + x4.y * w4.y + x4.z * w4.z + x4.w * w4.w;
    }
    out[(size_t)node * DN + tid] = acc;
  }
}

extern "C" void kernel_launch(void* const* d_in, const int* in_sizes, int n_in,
                              void* d_out, int out_size, void* d_ws, size_t ws_size,
                              hipStream_t stream) {
  const int n = in_sizes[0];
  sniff_mask_kernel<<<1, 1, 0, stream>>>((const unsigned char*)d_in[5], (int*)d_ws);
  tgat_fused<<<n, 256, 0, stream>>>(
      (const int*)d_in[0],  (const float*)d_in[1],  (const int*)d_in[2],
      (const float*)d_in[3],(const int*)d_in[4],    d_in[5],
      (const float*)d_in[6],(const float*)d_in[7],  (const float*)d_in[8],
      (const float*)d_in[9],(const float*)d_in[10],
      (const float*)d_in[11],(const float*)d_in[12],
      (const float*)d_in[13],(const float*)d_in[14],
      (const float*)d_in[15],(const float*)d_in[16],
      (const float*)d_in[17],(const float*)d_in[18],
      (const float*)d_in[19],(const float*)d_in[20],
      (const float*)d_in[21],(const float*)d_in[22],
      (float*)d_out, (const int*)d_ws);
}